// Round 5
// baseline (169.240 us; speedup 1.0000x reference)
//
#include <hip/hip_runtime.h>

#define NATOMS 64
#define VDIM 100
#define FDIM 128
#define HDIM 256
#define NCONV 4

typedef __bf16 bf16x8 __attribute__((ext_vector_type(8)));
typedef __bf16 bf16x4 __attribute__((ext_vector_type(4)));
typedef float f32x4 __attribute__((ext_vector_type(4)));

__device__ __forceinline__ float lrelu(float x) {
  return x >= 0.0f ? x : 0.01f * x;
}

// ---------------- kernel 0: pack weights into per-fragment order ----------------
// Layout: [n16 tile 0..7][ks 0..3][lane 0..63][e 0..7] bf16; for lane
// (g=lane>>4, lr=lane&15): element = W[k][n], n = n16*16+lr, k = ks*32+g*8+e.
__global__ void prep_weights(const float* __restrict__ Wi,
                             const float* __restrict__ Wc,
                             __bf16* __restrict__ WtI,
                             __bf16* __restrict__ WtC) {
  int idx = blockIdx.x * 256 + threadIdx.x;  // 81920 total
  int e = idx & 7;
  int lane = (idx >> 3) & 63;
  int ks = (idx >> 9) & 3;
  int n16 = (idx >> 11) & 7;
  int l = idx >> 14;  // 0 = init, 1..4 = conv layers
  int n = n16 * 16 + (lane & 15);
  int k = ks * 32 + (lane >> 4) * 8 + e;
  if (l == 0) {
    WtI[idx] = (__bf16)(k < VDIM ? Wi[k * FDIM + n] : 0.0f);
  } else {
    WtC[(l - 1) * 16384 + (idx & 16383)] =
        (__bf16)Wc[(l - 1) * FDIM * FDIM + k * FDIM + n];
  }
}

// conv matmul: acc = buf @ W ; epilogue produces agg A-frags in-register
// (cross-lane shfl relayout) or pools (final layer).
template <bool PRODUCE_FRAG>
__device__ __forceinline__ void conv_step(
    const __bf16* __restrict__ Wt, const float* __restrict__ bias,
    const __bf16* __restrict__ bufIn, bf16x8 xfrag[2][2], float psum[2],
    const int w, const int lane) {
  const int lr = lane & 15;
  const int g = lane >> 4;
  const int k0 = g * 8;
  f32x4 acc[2][4];
#pragma unroll
  for (int ni = 0; ni < 2; ++ni)
#pragma unroll
    for (int mi = 0; mi < 4; ++mi) acc[ni][mi] = {0.f, 0.f, 0.f, 0.f};
#pragma unroll
  for (int ks = 0; ks < 4; ++ks) {
    bf16x8 bfrag[2], afrag[4];
#pragma unroll
    for (int ni = 0; ni < 2; ++ni)
      bfrag[ni] = *(const bf16x8*)&Wt[(((2 * w + ni) * 4 + ks) * 64 + lane) * 8];
#pragma unroll
    for (int mi = 0; mi < 4; ++mi) {
      int m = mi * 16 + lr;
      afrag[mi] = *(const bf16x8*)&bufIn[m * 128 + ((ks * 32 + k0) ^ ((m & 7) << 3))];
    }
#pragma unroll
    for (int ni = 0; ni < 2; ++ni)
#pragma unroll
      for (int mi = 0; mi < 4; ++mi)
        acc[ni][mi] = __builtin_amdgcn_mfma_f32_16x16x32_bf16(
            afrag[mi], bfrag[ni], acc[ni][mi], 0, 0, 0);
  }
#pragma unroll
  for (int ni = 0; ni < 2; ++ni) {
    float bv = bias[(2 * w + ni) * 16 + lr];
    if constexpr (PRODUCE_FRAG) {
      uint2 d[4];
#pragma unroll
      for (int mi = 0; mi < 4; ++mi) {
        bf16x4 o;
#pragma unroll
        for (int j = 0; j < 4; ++j) o[j] = (__bf16)lrelu(acc[ni][mi][j] + bv);
        d[mi] = __builtin_bit_cast(uint2, o);
      }
      // relayout D-frag -> agg A-frag (atoms into k dim, features stay rows)
#pragma unroll
      for (int ksp = 0; ksp < 2; ++ksp) {
        unsigned r[4];
#pragma unroll
        for (int q = 0; q < 4; ++q) {
          int src = (2 * (g & 1) + (q >> 1)) * 16 + lr;
          unsigned lo = (q & 1) ? d[2 * ksp].y : d[2 * ksp].x;
          unsigned hi = (q & 1) ? d[2 * ksp + 1].y : d[2 * ksp + 1].x;
          unsigned va = (unsigned)__shfl((int)lo, src);
          unsigned vb = (unsigned)__shfl((int)hi, src);
          r[q] = (g >> 1) ? vb : va;
        }
        xfrag[ni][ksp] =
            __builtin_bit_cast(bf16x8, make_uint4(r[0], r[1], r[2], r[3]));
      }
    } else {
      float s = 0.f;
#pragma unroll
      for (int mi = 0; mi < 4; ++mi)
#pragma unroll
        for (int j = 0; j < 4; ++j) s += lrelu(acc[ni][mi][j] + bv);
      psum[ni] = s;
    }
  }
}

// aggregation: aggT = xT @ A (A sym 0/1, B-frags in regs), scale by rdg -> bufOut
__device__ __forceinline__ void agg_step(const bf16x8 abfrag[4][2],
                                         const bf16x8 xfrag[2][2],
                                         __bf16* __restrict__ bufOut,
                                         const float rdgv[4], const int w,
                                         const int lane) {
  const int lr = lane & 15;
  const int g = lane >> 4;
  f32x4 acc[2][4];
#pragma unroll
  for (int mi = 0; mi < 2; ++mi)
#pragma unroll
    for (int ni = 0; ni < 4; ++ni) acc[mi][ni] = {0.f, 0.f, 0.f, 0.f};
#pragma unroll
  for (int ks = 0; ks < 2; ++ks)
#pragma unroll
    for (int mi = 0; mi < 2; ++mi)
#pragma unroll
      for (int ni = 0; ni < 4; ++ni)
        acc[mi][ni] = __builtin_amdgcn_mfma_f32_16x16x32_bf16(
            xfrag[mi][ks], abfrag[ni][ks], acc[mi][ni], 0, 0, 0);
#pragma unroll
  for (int ni = 0; ni < 4; ++ni) {
    float rv = rdgv[ni];
    int a = ni * 16 + lr;
#pragma unroll
    for (int mi = 0; mi < 2; ++mi) {
      int f0r = (2 * w + mi) * 16 + g * 4;
      bf16x4 o;
#pragma unroll
      for (int j = 0; j < 4; ++j) o[j] = (__bf16)(acc[mi][ni][j] * rv);
      *(bf16x4*)&bufOut[a * 128 + (f0r ^ ((a & 7) << 3))] = o;
    }
  }
}

// ---------------- kernel 1: fused GCN, one molecule per block ----------------
// NOTE: no min-waves launch_bounds arg — testing whether it was capping
// runtime residency at ~4 waves/EU (R3/R4 both stuck at 41% occupancy).
__launch_bounds__(256)
__global__ void gcn_mfma(const float* __restrict__ node,
                         const float* __restrict__ adj,
                         const __bf16* __restrict__ WtI,
                         const __bf16* __restrict__ WtC,
                         const float* __restrict__ b_init,
                         const float* __restrict__ b_conv,
                         float* __restrict__ g_out) {
  __shared__ __align__(16) __bf16 sRow[NATOMS * FDIM];   // 16 KB
  __shared__ __align__(16) __bf16 sAdj[NATOMS * NATOMS]; // 8 KB
  __shared__ float sRdg[NATOMS];                         // 256 B

  const int b = blockIdx.x;
  const int t = threadIdx.x;
  const int lane = t & 63;
  const int w = t >> 6;
  const int lr = lane & 15;
  const int k0 = (lane >> 4) * 8;

  // ---- stage adjacency (bf16 0/1, swizzled) + shuffle-reduced degrees ----
  {
    const float* adjB = adj + (size_t)b * NATOMS * NATOMS;
#pragma unroll
    for (int half = 0; half < 2; ++half) {
      int n = (t >> 3) + half * 32;
      int gi = t & 7;
      float4 a0 = *(const float4*)&adjB[n * 64 + gi * 8];
      float4 a1 = *(const float4*)&adjB[n * 64 + gi * 8 + 4];
      bf16x8 v;
      v[0] = (__bf16)a0.x; v[1] = (__bf16)a0.y; v[2] = (__bf16)a0.z; v[3] = (__bf16)a0.w;
      v[4] = (__bf16)a1.x; v[5] = (__bf16)a1.y; v[6] = (__bf16)a1.z; v[7] = (__bf16)a1.w;
      *(bf16x8*)&sAdj[n * 64 + ((gi * 8) ^ ((n & 7) << 3))] = v;
      float p = a0.x + a0.y + a0.z + a0.w + a1.x + a1.y + a1.z + a1.w;
      p += __shfl_xor(p, 1); p += __shfl_xor(p, 2); p += __shfl_xor(p, 4);
      if (gi == 0) sRdg[n] = 1.0f / fmaxf(p, 1.0f);
    }
  }
  // ---- stage node -> sRow [atom][128] bf16, zero-pad k>=100, swizzled ----
  {
    const float* nodeB = node + (size_t)b * NATOMS * VDIM;
#pragma unroll
    for (int u0 = 0; u0 < 4; ++u0) {
      int u = t + 256 * u0;
      int n = u >> 4, gi = u & 15, kk = gi * 8;
      bf16x8 v;
      if (kk + 8 <= VDIM) {
        float4 a0 = *(const float4*)&nodeB[n * VDIM + kk];
        float4 a1 = *(const float4*)&nodeB[n * VDIM + kk + 4];
        v[0] = (__bf16)a0.x; v[1] = (__bf16)a0.y; v[2] = (__bf16)a0.z; v[3] = (__bf16)a0.w;
        v[4] = (__bf16)a1.x; v[5] = (__bf16)a1.y; v[6] = (__bf16)a1.z; v[7] = (__bf16)a1.w;
      } else {
#pragma unroll
        for (int i = 0; i < 8; ++i)
          v[i] = (__bf16)((kk + i < VDIM) ? nodeB[n * VDIM + kk + i] : 0.0f);
      }
      *(bf16x8*)&sRow[n * 128 + (kk ^ ((n & 7) << 3))] = v;
    }
  }
  __syncthreads();  // BAR1: staging visible

  // ---- hoist adjacency B-frags into registers (reused by all 4 agg layers) ----
  bf16x8 abfrag[4][2];
#pragma unroll
  for (int ni = 0; ni < 4; ++ni)
#pragma unroll
    for (int ks = 0; ks < 2; ++ks) {
      int n = ni * 16 + lr;
      abfrag[ni][ks] = *(const bf16x8*)&sAdj[n * 64 + ((ks * 32 + k0) ^ ((n & 7) << 3))];
    }
  float rdgv[4];
#pragma unroll
  for (int ni = 0; ni < 4; ++ni) rdgv[ni] = sRdg[ni * 16 + lr];

  bf16x8 xfrag[2][2];
  float psum[2];

  conv_step<true>(WtI, b_init, sRow, xfrag, psum, w, lane);
  __syncthreads();  // BAR2: sRow reads done; writable by agg

#pragma unroll
  for (int l = 0; l < NCONV; ++l) {
    agg_step(abfrag, xfrag, sRow, rdgv, w, lane);
    __syncthreads();  // RAW on sRow
    if (l < NCONV - 1) {
      conv_step<true>(WtC + l * 16384, b_conv + l * FDIM, sRow, xfrag, psum, w, lane);
      __syncthreads();  // WAR: sRow readers done before next agg writes
    } else {
      conv_step<false>(WtC + l * 16384, b_conv + l * FDIM, sRow, xfrag, psum, w, lane);
    }
  }

  // ---- mean pool: reduce psum over the 4 lane-groups, write 32 feats/wave ----
#pragma unroll
  for (int ni = 0; ni < 2; ++ni) {
    float s = psum[ni];
    s += __shfl_xor(s, 16);
    s += __shfl_xor(s, 32);
    if (lane < 16)
      g_out[(size_t)b * FDIM + (2 * w + ni) * 16 + lane] = s * (1.0f / 64.0f);
  }
}

// ---------------- kernel 2: FC head, 16 molecules per block ----------------
__launch_bounds__(256, 2)
__global__ void head_fc(const float* __restrict__ g,
                        const float* __restrict__ W_fc0, const float* __restrict__ b_fc0,
                        const float* __restrict__ W_fc1, const float* __restrict__ b_fc1,
                        const float* __restrict__ W_out, const float* __restrict__ b_out,
                        float* __restrict__ out) {
  __shared__ __align__(16) float sG[16 * FDIM];
  __shared__ float sH[16 * (HDIM + 1)];
  __shared__ float sRed[4 * 16];

  const int t = threadIdx.x;
  const int lane = t & 63;
  const int w = t >> 6;
  const int r0 = blockIdx.x * 16;

  {
    const float4* gs = (const float4*)(g + (size_t)r0 * FDIM);
    float4* gd = (float4*)sG;
#pragma unroll
    for (int u = 0; u < 2; ++u) gd[t + 256 * u] = gs[t + 256 * u];
  }
  __syncthreads();

  float acc[16];
  {
    float bv = b_fc0[t];
#pragma unroll
    for (int r = 0; r < 16; ++r) acc[r] = bv;
    for (int k = 0; k < FDIM; ++k) {
      float wv = W_fc0[k * HDIM + t];
#pragma unroll
      for (int r = 0; r < 16; ++r) acc[r] += sG[r * FDIM + k] * wv;
    }
#pragma unroll
    for (int r = 0; r < 16; ++r) sH[r * (HDIM + 1) + t] = lrelu(acc[r]);
  }
  __syncthreads();

  {
    float bv = b_fc1[t];
#pragma unroll
    for (int r = 0; r < 16; ++r) acc[r] = bv;
    for (int k = 0; k < HDIM; ++k) {
      float wv = W_fc1[k * HDIM + t];
#pragma unroll
      for (int r = 0; r < 16; ++r) acc[r] += sH[r * (HDIM + 1) + k] * wv;
    }
    float wo = W_out[t];
#pragma unroll
    for (int r = 0; r < 16; ++r) acc[r] = lrelu(acc[r]) * wo;
  }
#pragma unroll
  for (int r = 0; r < 16; ++r) {
    float v = acc[r];
    v += __shfl_down(v, 32); v += __shfl_down(v, 16); v += __shfl_down(v, 8);
    v += __shfl_down(v, 4);  v += __shfl_down(v, 2);  v += __shfl_down(v, 1);
    if (lane == 0) sRed[w * 16 + r] = v;
  }
  __syncthreads();
  if (t < 16)
    out[r0 + t] = sRed[t] + sRed[16 + t] + sRed[32 + t] + sRed[48 + t] + b_out[0];
}

extern "C" void kernel_launch(void* const* d_in, const int* in_sizes, int n_in,
                              void* d_out, int out_size, void* d_ws, size_t ws_size,
                              hipStream_t stream) {
  (void)in_sizes; (void)n_in; (void)ws_size; (void)out_size;
  const float* node   = (const float*)d_in[0];
  const float* adj    = (const float*)d_in[1];
  const float* W_init = (const float*)d_in[2];
  const float* b_init = (const float*)d_in[3];
  const float* W_conv = (const float*)d_in[4];
  const float* b_conv = (const float*)d_in[5];
  const float* W_fc0  = (const float*)d_in[6];
  const float* b_fc0  = (const float*)d_in[7];
  const float* W_fc1  = (const float*)d_in[8];
  const float* b_fc1  = (const float*)d_in[9];
  const float* W_out  = (const float*)d_in[10];
  const float* b_out  = (const float*)d_in[11];
  float* out = (float*)d_out;

  // ws layout: WtI bf16[16384] | WtC bf16[65536] | g f32[4096*128]
  __bf16* WtI = (__bf16*)d_ws;
  __bf16* WtC = WtI + 16384;
  float* g = (float*)((char*)d_ws + 160 * 1024);

  prep_weights<<<320, 256, 0, stream>>>(W_init, W_conv, WtI, WtC);
  gcn_mfma<<<4096, 256, 0, stream>>>(node, adj, WtI, WtC, b_init, b_conv, g);
  head_fc<<<256, 256, 0, stream>>>(g, W_fc0, b_fc0, W_fc1, b_fc1, W_out, b_out, out);
}

// Round 6
// 144.779 us; speedup vs baseline: 1.1690x; 1.1690x over previous
//
#include <hip/hip_runtime.h>

#define NATOMS 64
#define VDIM 100
#define FDIM 128
#define HDIM 256
#define NCONV 4

typedef __bf16 bf16x8 __attribute__((ext_vector_type(8)));
typedef __bf16 bf16x4 __attribute__((ext_vector_type(4)));
typedef float f32x4 __attribute__((ext_vector_type(4)));

__device__ __forceinline__ float lrelu(float x) {
  return x >= 0.0f ? x : 0.01f * x;
}

// ---------------- kernel 0: pack weights into per-fragment order ----------------
// Layout: [n16 tile 0..7][ks 0..3][lane 0..63][e 0..7] bf16; for lane
// (g=lane>>4, lr=lane&15): element = W[k][n], n = n16*16+lr, k = ks*32+g*8+e.
__global__ void prep_weights(const float* __restrict__ Wi,
                             const float* __restrict__ Wc,
                             __bf16* __restrict__ WtI,
                             __bf16* __restrict__ WtC) {
  int idx = blockIdx.x * 256 + threadIdx.x;  // 81920 total
  int e = idx & 7;
  int lane = (idx >> 3) & 63;
  int ks = (idx >> 9) & 3;
  int n16 = (idx >> 11) & 7;
  int l = idx >> 14;  // 0 = init, 1..4 = conv layers
  int n = n16 * 16 + (lane & 15);
  int k = ks * 32 + (lane >> 4) * 8 + e;
  if (l == 0) {
    WtI[idx] = (__bf16)(k < VDIM ? Wi[k * FDIM + n] : 0.0f);
  } else {
    WtC[(l - 1) * 16384 + (idx & 16383)] =
        (__bf16)Wc[(l - 1) * FDIM * FDIM + k * FDIM + n];
  }
}

// conv matmul: acc = sRow @ W ; epilogue produces agg A-frags in-register
// (cross-lane shfl relayout) or pools (final layer).
template <bool PRODUCE_FRAG>
__device__ __forceinline__ void conv_step(
    const __bf16* __restrict__ Wt, const float* __restrict__ bias,
    const __bf16* __restrict__ sRow, bf16x8 xfrag[2][2], float psum[2],
    const int w, const int lane) {
  const int lr = lane & 15;
  const int g = lane >> 4;
  const int k0 = g * 8;
  f32x4 acc[2][4];
#pragma unroll
  for (int ni = 0; ni < 2; ++ni)
#pragma unroll
    for (int mi = 0; mi < 4; ++mi) acc[ni][mi] = {0.f, 0.f, 0.f, 0.f};
#pragma unroll
  for (int ks = 0; ks < 4; ++ks) {
    bf16x8 bfrag[2], afrag[4];
#pragma unroll
    for (int ni = 0; ni < 2; ++ni)
      bfrag[ni] = *(const bf16x8*)&Wt[(((2 * w + ni) * 4 + ks) * 64 + lane) * 8];
#pragma unroll
    for (int mi = 0; mi < 4; ++mi) {
      int m = mi * 16 + lr;
      afrag[mi] = *(const bf16x8*)&sRow[m * 128 + ((ks * 32 + k0) ^ ((m & 7) << 3))];
    }
#pragma unroll
    for (int ni = 0; ni < 2; ++ni)
#pragma unroll
      for (int mi = 0; mi < 4; ++mi)
        acc[ni][mi] = __builtin_amdgcn_mfma_f32_16x16x32_bf16(
            afrag[mi], bfrag[ni], acc[ni][mi], 0, 0, 0);
  }
#pragma unroll
  for (int ni = 0; ni < 2; ++ni) {
    float bv = bias[(2 * w + ni) * 16 + lr];
    if constexpr (PRODUCE_FRAG) {
      uint2 d[4];
#pragma unroll
      for (int mi = 0; mi < 4; ++mi) {
        bf16x4 o;
#pragma unroll
        for (int j = 0; j < 4; ++j) o[j] = (__bf16)lrelu(acc[ni][mi][j] + bv);
        d[mi] = __builtin_bit_cast(uint2, o);
      }
      // relayout D-frag -> agg A-frag (atoms into k dim, features stay rows)
#pragma unroll
      for (int ksp = 0; ksp < 2; ++ksp) {
        unsigned r[4];
#pragma unroll
        for (int q = 0; q < 4; ++q) {
          int src = (2 * (g & 1) + (q >> 1)) * 16 + lr;
          unsigned lo = (q & 1) ? d[2 * ksp].y : d[2 * ksp].x;
          unsigned hi = (q & 1) ? d[2 * ksp + 1].y : d[2 * ksp + 1].x;
          unsigned va = (unsigned)__shfl((int)lo, src);
          unsigned vb = (unsigned)__shfl((int)hi, src);
          r[q] = (g >> 1) ? vb : va;
        }
        xfrag[ni][ksp] =
            __builtin_bit_cast(bf16x8, make_uint4(r[0], r[1], r[2], r[3]));
      }
    } else {
      float s = 0.f;
#pragma unroll
      for (int mi = 0; mi < 4; ++mi)
#pragma unroll
        for (int j = 0; j < 4; ++j) s += lrelu(acc[ni][mi][j] + bv);
      psum[ni] = s;
    }
  }
}

// aggregation: aggT = xT @ A (A symmetric 0/1), scale atom-columns by rdg -> sRow
__device__ __forceinline__ void agg_step(const __bf16* __restrict__ sAdj,
                                         const bf16x8 xfrag[2][2],
                                         __bf16* __restrict__ sRow,
                                         const float rdgv[4], const int w,
                                         const int lane) {
  const int lr = lane & 15;
  const int g = lane >> 4;
  const int k0 = g * 8;
  f32x4 acc[2][4];
#pragma unroll
  for (int mi = 0; mi < 2; ++mi)
#pragma unroll
    for (int ni = 0; ni < 4; ++ni) acc[mi][ni] = {0.f, 0.f, 0.f, 0.f};
#pragma unroll
  for (int ks = 0; ks < 2; ++ks) {
    bf16x8 bfrag[4];
#pragma unroll
    for (int ni = 0; ni < 4; ++ni) {
      int n = ni * 16 + lr;
      bfrag[ni] = *(const bf16x8*)&sAdj[n * 64 + ((ks * 32 + k0) ^ ((n & 7) << 3))];
    }
#pragma unroll
    for (int mi = 0; mi < 2; ++mi)
#pragma unroll
      for (int ni = 0; ni < 4; ++ni)
        acc[mi][ni] = __builtin_amdgcn_mfma_f32_16x16x32_bf16(
            xfrag[mi][ks], bfrag[ni], acc[mi][ni], 0, 0, 0);
  }
#pragma unroll
  for (int ni = 0; ni < 4; ++ni) {
    float rv = rdgv[ni];
    int a = ni * 16 + lr;
#pragma unroll
    for (int mi = 0; mi < 2; ++mi) {
      int f0r = (2 * w + mi) * 16 + g * 4;
      bf16x4 o;
#pragma unroll
      for (int j = 0; j < 4; ++j) o[j] = (__bf16)(acc[mi][ni][j] * rv);
      *(bf16x4*)&sRow[a * 128 + (f0r ^ ((a & 7) << 3))] = o;
    }
  }
}

// ---------------- kernel 1: fused GCN, one molecule per block ----------------
// (256,8): request 8 waves/EU -> keeps VGPR <= 64 (the R5 regression was the
// 64-VGPR occupancy cliff at VGPR=68); LDS 24.5 KB then allows 6 blocks/CU.
__launch_bounds__(256, 8)
__global__ void gcn_mfma(const float* __restrict__ node,
                         const float* __restrict__ adj,
                         const __bf16* __restrict__ WtI,
                         const __bf16* __restrict__ WtC,
                         const float* __restrict__ b_init,
                         const float* __restrict__ b_conv,
                         float* __restrict__ g_out) {
  __shared__ __align__(16) __bf16 sRow[NATOMS * FDIM];   // 16 KB
  __shared__ __align__(16) __bf16 sAdj[NATOMS * NATOMS]; // 8 KB
  __shared__ float sRdg[NATOMS];                         // 256 B

  const int b = blockIdx.x;
  const int t = threadIdx.x;
  const int lane = t & 63;
  const int w = t >> 6;

  // ---- stage adjacency (bf16 0/1, swizzled) + shuffle-reduced degrees ----
  {
    const float* adjB = adj + (size_t)b * NATOMS * NATOMS;
#pragma unroll
    for (int half = 0; half < 2; ++half) {
      int n = (t >> 3) + half * 32;
      int gi = t & 7;
      float4 a0 = *(const float4*)&adjB[n * 64 + gi * 8];
      float4 a1 = *(const float4*)&adjB[n * 64 + gi * 8 + 4];
      bf16x8 v;
      v[0] = (__bf16)a0.x; v[1] = (__bf16)a0.y; v[2] = (__bf16)a0.z; v[3] = (__bf16)a0.w;
      v[4] = (__bf16)a1.x; v[5] = (__bf16)a1.y; v[6] = (__bf16)a1.z; v[7] = (__bf16)a1.w;
      *(bf16x8*)&sAdj[n * 64 + ((gi * 8) ^ ((n & 7) << 3))] = v;
      float p = a0.x + a0.y + a0.z + a0.w + a1.x + a1.y + a1.z + a1.w;
      p += __shfl_xor(p, 1); p += __shfl_xor(p, 2); p += __shfl_xor(p, 4);
      if (gi == 0) sRdg[n] = 1.0f / fmaxf(p, 1.0f);
    }
  }
  // ---- stage node -> sRow [atom][128] bf16, zero-pad k>=100, swizzled ----
  {
    const float* nodeB = node + (size_t)b * NATOMS * VDIM;
#pragma unroll
    for (int u0 = 0; u0 < 4; ++u0) {
      int u = t + 256 * u0;
      int n = u >> 4, gi = u & 15, kk = gi * 8;
      bf16x8 v;
      if (kk + 8 <= VDIM) {
        float4 a0 = *(const float4*)&nodeB[n * VDIM + kk];
        float4 a1 = *(const float4*)&nodeB[n * VDIM + kk + 4];
        v[0] = (__bf16)a0.x; v[1] = (__bf16)a0.y; v[2] = (__bf16)a0.z; v[3] = (__bf16)a0.w;
        v[4] = (__bf16)a1.x; v[5] = (__bf16)a1.y; v[6] = (__bf16)a1.z; v[7] = (__bf16)a1.w;
      } else {
#pragma unroll
        for (int i = 0; i < 8; ++i)
          v[i] = (__bf16)((kk + i < VDIM) ? nodeB[n * VDIM + kk + i] : 0.0f);
      }
      *(bf16x8*)&sRow[n * 128 + (kk ^ ((n & 7) << 3))] = v;
    }
  }
  __syncthreads();

  float rdgv[4];
#pragma unroll
  for (int ni = 0; ni < 4; ++ni) rdgv[ni] = sRdg[ni * 16 + (lane & 15)];

  bf16x8 xfrag[2][2];
  float psum[2];

  conv_step<true>(WtI, b_init, sRow, xfrag, psum, w, lane);
  __syncthreads();

#pragma unroll
  for (int l = 0; l < NCONV; ++l) {
    agg_step(sAdj, xfrag, sRow, rdgv, w, lane);
    __syncthreads();
    if (l < NCONV - 1) {
      conv_step<true>(WtC + l * 16384, b_conv + l * FDIM, sRow, xfrag, psum, w, lane);
      __syncthreads();
    } else {
      conv_step<false>(WtC + l * 16384, b_conv + l * FDIM, sRow, xfrag, psum, w, lane);
    }
  }

  // ---- mean pool: reduce psum over the 4 lane-groups, write 32 feats/wave ----
#pragma unroll
  for (int ni = 0; ni < 2; ++ni) {
    float s = psum[ni];
    s += __shfl_xor(s, 16);
    s += __shfl_xor(s, 32);
    if (lane < 16)
      g_out[(size_t)b * FDIM + (2 * w + ni) * 16 + lane] = s * (1.0f / 64.0f);
  }
}

// ---------------- kernel 2: FC head, 16 molecules per block ----------------
__launch_bounds__(256, 2)
__global__ void head_fc(const float* __restrict__ g,
                        const float* __restrict__ W_fc0, const float* __restrict__ b_fc0,
                        const float* __restrict__ W_fc1, const float* __restrict__ b_fc1,
                        const float* __restrict__ W_out, const float* __restrict__ b_out,
                        float* __restrict__ out) {
  __shared__ __align__(16) float sG[16 * FDIM];
  __shared__ float sH[16 * (HDIM + 1)];
  __shared__ float sRed[4 * 16];

  const int t = threadIdx.x;
  const int lane = t & 63;
  const int w = t >> 6;
  const int r0 = blockIdx.x * 16;

  {
    const float4* gs = (const float4*)(g + (size_t)r0 * FDIM);
    float4* gd = (float4*)sG;
#pragma unroll
    for (int u = 0; u < 2; ++u) gd[t + 256 * u] = gs[t + 256 * u];
  }
  __syncthreads();

  float acc[16];
  {
    float bv = b_fc0[t];
#pragma unroll
    for (int r = 0; r < 16; ++r) acc[r] = bv;
    for (int k = 0; k < FDIM; ++k) {
      float wv = W_fc0[k * HDIM + t];
#pragma unroll
      for (int r = 0; r < 16; ++r) acc[r] += sG[r * FDIM + k] * wv;
    }
#pragma unroll
    for (int r = 0; r < 16; ++r) sH[r * (HDIM + 1) + t] = lrelu(acc[r]);
  }
  __syncthreads();

  {
    float bv = b_fc1[t];
#pragma unroll
    for (int r = 0; r < 16; ++r) acc[r] = bv;
    for (int k = 0; k < HDIM; ++k) {
      float wv = W_fc1[k * HDIM + t];
#pragma unroll
      for (int r = 0; r < 16; ++r) acc[r] += sH[r * (HDIM + 1) + k] * wv;
    }
    float wo = W_out[t];
#pragma unroll
    for (int r = 0; r < 16; ++r) acc[r] = lrelu(acc[r]) * wo;
  }
#pragma unroll
  for (int r = 0; r < 16; ++r) {
    float v = acc[r];
    v += __shfl_down(v, 32); v += __shfl_down(v, 16); v += __shfl_down(v, 8);
    v += __shfl_down(v, 4);  v += __shfl_down(v, 2);  v += __shfl_down(v, 1);
    if (lane == 0) sRed[w * 16 + r] = v;
  }
  __syncthreads();
  if (t < 16)
    out[r0 + t] = sRed[t] + sRed[16 + t] + sRed[32 + t] + sRed[48 + t] + b_out[0];
}

extern "C" void kernel_launch(void* const* d_in, const int* in_sizes, int n_in,
                              void* d_out, int out_size, void* d_ws, size_t ws_size,
                              hipStream_t stream) {
  (void)in_sizes; (void)n_in; (void)ws_size; (void)out_size;
  const float* node   = (const float*)d_in[0];
  const float* adj    = (const float*)d_in[1];
  const float* W_init = (const float*)d_in[2];
  const float* b_init = (const float*)d_in[3];
  const float* W_conv = (const float*)d_in[4];
  const float* b_conv = (const float*)d_in[5];
  const float* W_fc0  = (const float*)d_in[6];
  const float* b_fc0  = (const float*)d_in[7];
  const float* W_fc1  = (const float*)d_in[8];
  const float* b_fc1  = (const float*)d_in[9];
  const float* W_out  = (const float*)d_in[10];
  const float* b_out  = (const float*)d_in[11];
  float* out = (float*)d_out;

  // ws layout: WtI bf16[16384] | WtC bf16[65536] | g f32[4096*128]
  __bf16* WtI = (__bf16*)d_ws;
  __bf16* WtC = WtI + 16384;
  float* g = (float*)((char*)d_ws + 160 * 1024);

  prep_weights<<<320, 256, 0, stream>>>(W_init, W_conv, WtI, WtC);
  gcn_mfma<<<4096, 256, 0, stream>>>(node, adj, WtI, WtC, b_init, b_conv, g);
  head_fc<<<256, 256, 0, stream>>>(g, W_fc0, b_fc0, W_fc1, b_fc1, W_out, b_out, out);
}